// Round 2
// baseline (451.124 us; speedup 1.0000x reference)
//
#include <hip/hip_runtime.h>

#define D_CH 32
#define L_LEN 65536
#define W_TAPS 5
#define TPB 256
#define PT 8                       // floats per thread (was 16)
#define CHUNK (TPB * PT)           // 2048 floats per block
#define TILES (L_LEN / CHUNK)      // 32

typedef float float4v __attribute__((ext_vector_type(4)));
typedef float float2v __attribute__((ext_vector_type(2)));

// Round-2 change: halve per-thread footprint (acc 64->32 VGPR, vf 32->16)
// to raise occupancy (theory: latency-bound at ~12 waves/CU), double the
// grid (2048->4096 blocks), and move halo boundary clamps into a
// block-uniform `edge` branch so 30/32 tiles run a select-free fast path.
// Interior tiles read halos across tile boundaries (always in-bounds
// within the channel); only tile 0 / tile 31 blocks clamp+zero.
__global__ __launch_bounds__(TPB, 4) void grouped_conv1d_kernel(
    const float* __restrict__ x,   // (32, 32, L) fp32
    const float* __restrict__ k0,  // (4, 8, 5) fp32
    const float* __restrict__ k1,
    const float* __restrict__ k2,
    const float* __restrict__ k3,
    float* __restrict__ out)       // (32, 16, L) fp32
{
    const int bid  = blockIdx.x;
    const int tile = bid & (TILES - 1);
    const int g    = (bid >> 5) & 3;
    const int b    = bid >> 7;

    const int wv   = (int)threadIdx.x >> 6;   // wave id (0..3)
    const int ln   = (int)threadIdx.x & 63;
    // segment q (q=0,1) covers floats [base + q*256, base + q*256 + 4)
    const int base = tile * CHUNK + wv * (PT * 64) + ln * 4;

    const bool edge = (tile == 0) || (tile == TILES - 1);  // block-uniform

    const float* kp = (g == 0) ? k0 : (g == 1) ? k1 : (g == 2) ? k2 : k3;

    float acc[4][PT];               // [out_ch][q*4 + i]
#pragma unroll
    for (int o = 0; o < 4; ++o)
#pragma unroll
        for (int i = 0; i < PT; ++i) acc[o][i] = 0.f;

    const float* xb = x + ((size_t)b * D_CH + (size_t)g * 8) * L_LEN;

#pragma unroll
    for (int c = 0; c < 8; ++c) {
        const float* xc = xb + (size_t)c * L_LEN;

        // vf[q][j] = x[P + j - 2], P = base + q*256
        float vf[2][8];
#pragma unroll
        for (int q = 0; q < 2; ++q) {
            const int P = base + q * 256;

            float4v m = *(const float4v*)(xc + P);       // coalesced 1KiB/wave
            vf[q][2] = m[0]; vf[q][3] = m[1]; vf[q][4] = m[2]; vf[q][5] = m[3];

            if (!edge) {
                // interior: halo always in-bounds, no selects
                float2v hl = *(const float2v*)(xc + P - 2);
                float2v hr = *(const float2v*)(xc + P + 4);
                vf[q][0] = hl[0]; vf[q][1] = hl[1];
                vf[q][6] = hr[0]; vf[q][7] = hr[1];
            } else {
                const int Pl = (P > 0) ? (P - 2) : 0;
                float2v hl = *(const float2v*)(xc + Pl);
                vf[q][0] = (P > 0) ? hl[0] : 0.f;
                vf[q][1] = (P > 0) ? hl[1] : 0.f;

                const bool rok = (P + 4 < L_LEN);
                const int Pr = rok ? (P + 4) : 0;
                float2v hr = *(const float2v*)(xc + Pr);
                vf[q][6] = rok ? hr[0] : 0.f;
                vf[q][7] = rok ? hr[1] : 0.f;
            }
        }

        // taps for this input channel (wave-uniform -> scalar loads)
        float kf[4][W_TAPS];
#pragma unroll
        for (int o = 0; o < 4; ++o)
#pragma unroll
            for (int w = 0; w < W_TAPS; ++w)
                kf[o][w] = kp[(o * 8 + c) * W_TAPS + w];

#pragma unroll
        for (int o = 0; o < 4; ++o)
#pragma unroll
            for (int w = 0; w < W_TAPS; ++w) {
                const float kk = kf[o][w];
#pragma unroll
                for (int q = 0; q < 2; ++q)
#pragma unroll
                    for (int i = 0; i < 4; ++i)
                        acc[o][q * 4 + i] += vf[q][i + w] * kk;
            }
    }

#pragma unroll
    for (int o = 0; o < 4; ++o) {
        float* op = out + (((size_t)b * 16 + (size_t)(g * 4 + o)) * L_LEN);
#pragma unroll
        for (int q = 0; q < 2; ++q) {
            float4v s;
#pragma unroll
            for (int i = 0; i < 4; ++i) s[i] = acc[o][4 * q + i];
            *(float4v*)(op + base + q * 256) = s;   // coalesced 1KiB/wave
        }
    }
}

extern "C" void kernel_launch(void* const* d_in, const int* in_sizes, int n_in,
                              void* d_out, int out_size, void* d_ws, size_t ws_size,
                              hipStream_t stream) {
    const float* x  = (const float*)d_in[0];
    const float* k0 = (const float*)d_in[1];
    const float* k1 = (const float*)d_in[2];
    const float* k2 = (const float*)d_in[3];
    const float* k3 = (const float*)d_in[4];
    float* out = (float*)d_out;

    const int blocks = 32 * 4 * TILES;  // 4096
    grouped_conv1d_kernel<<<blocks, TPB, 0, stream>>>(x, k0, k1, k2, k3, out);
}

// Round 3
// 405.414 us; speedup vs baseline: 1.1127x; 1.1127x over previous
//
#include <hip/hip_runtime.h>

#define D_CH 32
#define L_LEN 65536
#define W_TAPS 5
#define TPB 256
#define CHUNK 4096                 // floats per block
#define TILES (L_LEN / CHUNK)      // 16

typedef float float4v __attribute__((ext_vector_type(4)));
typedef float float2v __attribute__((ext_vector_type(2)));

// Round-3: pure revert to the round-1 kernel (406.1 µs verified).
// Evidence from round-2 counters: kernel traffic during dispatch is
// ~493 MB (403 MB algorithmic + ~139 MB harness poison-fill L3 flush),
// and rounds 0/1 ran that at ~6.2 TB/s ≈ 80 µs = the mixed-stream HBM
// roofline. Round-2's PT=8/4096-block variant broke the rate (2.9 TB/s);
// this layout is the known-good one.
// Each thread owns 4 segments of 4 floats spaced 256 floats apart; within
// a wave, lanes are 16B-contiguous -> every dwordx4 load/store is a fully
// coalesced 1KiB wave access. Halo = two 8B dwordx2 loads per segment.
__global__ __launch_bounds__(TPB) void grouped_conv1d_kernel(
    const float* __restrict__ x,   // (32, 32, L) fp32
    const float* __restrict__ k0,  // (4, 8, 5) fp32
    const float* __restrict__ k1,
    const float* __restrict__ k2,
    const float* __restrict__ k3,
    float* __restrict__ out)       // (32, 16, L) fp32
{
    const int bid  = blockIdx.x;
    const int tile = bid & (TILES - 1);
    const int g    = (bid >> 4) & 3;
    const int b    = bid >> 6;

    const int wv   = (int)threadIdx.x >> 6;   // wave id in block (0..3)
    const int ln   = (int)threadIdx.x & 63;   // lane
    // segment q covers floats [base + q*256, base + q*256 + 4)
    const int base = tile * CHUNK + wv * 1024 + ln * 4;

    const float* kp = (g == 0) ? k0 : (g == 1) ? k1 : (g == 2) ? k2 : k3;

    float acc[4][16];               // [out_ch][q*4 + i]
#pragma unroll
    for (int o = 0; o < 4; ++o)
#pragma unroll
        for (int i = 0; i < 16; ++i) acc[o][i] = 0.f;

    const float* xb = x + ((size_t)b * D_CH + (size_t)g * 8) * L_LEN;

#pragma unroll
    for (int c = 0; c < 8; ++c) {
        const float* xc = xb + (size_t)c * L_LEN;

        // vf[q][j] = x[P + j - 2], P = base + q*256
        float vf[4][8];
#pragma unroll
        for (int q = 0; q < 4; ++q) {
            const int P = base + q * 256;

            // main 4 floats: aligned, lane-contiguous (coalesced 1KiB/wave)
            float4v m = *(const float4v*)(xc + P);
            vf[q][2] = m[0]; vf[q][3] = m[1]; vf[q][4] = m[2]; vf[q][5] = m[3];

            // left halo x[P-2], x[P-1]; branchless clamp (junk discarded)
            const int Pl = (P > 0) ? (P - 2) : 0;
            float2v hl = *(const float2v*)(xc + Pl);
            vf[q][0] = (P > 0) ? hl[0] : 0.f;
            vf[q][1] = (P > 0) ? hl[1] : 0.f;

            // right halo x[P+4], x[P+5]
            const bool rok = (P + 4 < L_LEN);
            const int Pr = rok ? (P + 4) : 0;
            float2v hr = *(const float2v*)(xc + Pr);
            vf[q][6] = rok ? hr[0] : 0.f;
            vf[q][7] = rok ? hr[1] : 0.f;
        }

        // taps for this input channel (wave-uniform -> SGPR)
        float kf[4][W_TAPS];
#pragma unroll
        for (int o = 0; o < 4; ++o)
#pragma unroll
            for (int w = 0; w < W_TAPS; ++w)
                kf[o][w] = kp[(o * 8 + c) * W_TAPS + w];

#pragma unroll
        for (int o = 0; o < 4; ++o)
#pragma unroll
            for (int w = 0; w < W_TAPS; ++w) {
                const float kk = kf[o][w];
#pragma unroll
                for (int q = 0; q < 4; ++q)
#pragma unroll
                    for (int i = 0; i < 4; ++i)
                        acc[o][q * 4 + i] += vf[q][i + w] * kk;
            }
    }

#pragma unroll
    for (int o = 0; o < 4; ++o) {
        float* op = out + (((size_t)b * 16 + (size_t)(g * 4 + o)) * L_LEN);
#pragma unroll
        for (int q = 0; q < 4; ++q) {
            float4v s;
#pragma unroll
            for (int i = 0; i < 4; ++i) s[i] = acc[o][4 * q + i];
            *(float4v*)(op + base + q * 256) = s;   // coalesced 1KiB/wave
        }
    }
}

extern "C" void kernel_launch(void* const* d_in, const int* in_sizes, int n_in,
                              void* d_out, int out_size, void* d_ws, size_t ws_size,
                              hipStream_t stream) {
    const float* x  = (const float*)d_in[0];
    const float* k0 = (const float*)d_in[1];
    const float* k1 = (const float*)d_in[2];
    const float* k2 = (const float*)d_in[3];
    const float* k3 = (const float*)d_in[4];
    float* out = (float*)d_out;

    const int blocks = 32 * 4 * TILES;  // 2048
    grouped_conv1d_kernel<<<blocks, TPB, 0, stream>>>(x, k0, k1, k2, k3, out);
}